// Round 2
// baseline (6877.222 us; speedup 1.0000x reference)
//
#include <hip/hip_runtime.h>
#include <cstdint>

#define B_ 8
#define N_ 4096
#define CIN_ 64
#define COUT_ 128
#define R_ 32
#define R3_ 32768
#define GROUPS_ 8
#define EPS_ 1e-5f

// ---------------------------------------------------------------- batch stats
__global__ void k_batch_stats(const float* __restrict__ coords, float* __restrict__ bstats) {
    int b = blockIdx.x;
    int tid = threadIdx.x;
    __shared__ float rb[256];
    __shared__ float smean[3];
    const float* cb = coords + (size_t)b * N_ * 3;
    float sx = 0.f, sy = 0.f, sz = 0.f;
    for (int n = tid; n < N_; n += 256) {
        sx += cb[n * 3 + 0];
        sy += cb[n * 3 + 1];
        sz += cb[n * 3 + 2];
    }
    float vals[3] = {sx, sy, sz};
    for (int k = 0; k < 3; ++k) {
        rb[tid] = vals[k];
        __syncthreads();
        for (int s = 128; s > 0; s >>= 1) {
            if (tid < s) rb[tid] += rb[tid + s];
            __syncthreads();
        }
        if (tid == 0) smean[k] = rb[0] / (float)N_;
        __syncthreads();
    }
    float mx = smean[0], my = smean[1], mz = smean[2];
    float m2 = 0.f;
    for (int n = tid; n < N_; n += 256) {
        float dx = cb[n * 3 + 0] - mx, dy = cb[n * 3 + 1] - my, dz = cb[n * 3 + 2] - mz;
        m2 = fmaxf(m2, dx * dx + dy * dy + dz * dz);
    }
    rb[tid] = m2;
    __syncthreads();
    for (int s = 128; s > 0; s >>= 1) {
        if (tid < s) rb[tid] = fmaxf(rb[tid], rb[tid + s]);
        __syncthreads();
    }
    if (tid == 0) {
        bstats[b * 4 + 0] = mx;
        bstats[b * 4 + 1] = my;
        bstats[b * 4 + 2] = mz;
        bstats[b * 4 + 3] = 2.0f * sqrtf(rb[0]);
    }
}

// -------------------------------------------------- per-point coords + counts
__global__ void k_points(const float* __restrict__ coords, const float* __restrict__ bstats,
                         float* __restrict__ ncoords, int* __restrict__ flatidx,
                         float* __restrict__ cnt) {
    int idx = blockIdx.x * 256 + threadIdx.x;  // b*N + n
    int b = idx >> 12, n = idx & (N_ - 1);
    float scale = bstats[b * 4 + 3];
    int vi[3];
    for (int k = 0; k < 3; ++k) {
        float c = coords[((size_t)b * N_ + n) * 3 + k] - bstats[b * 4 + k];
        float nc = fminf(fmaxf((c / scale + 0.5f) * (float)R_, 0.0f), (float)(R_ - 1));
        ncoords[((size_t)b * N_ + n) * 3 + k] = nc;
        vi[k] = (int)rintf(nc);  // round half-to-even, matches jnp.round
    }
    int flat = (vi[0] * R_ + vi[1]) * R_ + vi[2];
    flatidx[idx] = flat;
    atomicAdd(&cnt[(size_t)b * R3_ + flat], 1.0f);
}

// ------------------------------------------------------------- scatter (sum)
// grid region is chunk-local: [CB, R3, 64]
__global__ void k_scatter(const float* __restrict__ feat, const int* __restrict__ flatidx,
                          float* __restrict__ grid, int b0) {
    int bid = blockIdx.x;               // CB * 64ci * 16 chunks
    int nch = bid & 15, ci = (bid >> 4) & 63, bl = bid >> 10;
    int b = b0 + bl;
    int n = nch * 256 + threadIdx.x;
    float v = feat[((size_t)b * CIN_ + ci) * N_ + n];
    int flat = flatidx[b * N_ + n];
    atomicAdd(&grid[((size_t)bl * R3_ + flat) * CIN_ + ci], v);
}

// ---------------------------------------------------------- divide by counts
__global__ void k_divide(float* __restrict__ grid, const float* __restrict__ cnt, int b0) {
    size_t idx4 = (size_t)blockIdx.x * 256 + threadIdx.x;  // < CB*R3*16
    size_t v = idx4 >> 4;                                  // bl*R3 + flat
    float c = cnt[v + (size_t)b0 * R3_];
    float s = 1.0f / fmaxf(c, 1.0f);
    float4* g = (float4*)grid;
    float4 x = g[idx4];
    x.x *= s; x.y *= s; x.z *= s; x.w *= s;
    g[idx4] = x;
}

// --------------------------------------------------------------- weight prep
// wT[t][ci][co] = w[co][ci][t],  t = kx*9+ky*3+kz
__global__ void k_wtrans(const float* __restrict__ w, float* __restrict__ wT, int Cin) {
    int idx = blockIdx.x * 256 + threadIdx.x;
    int total = 27 * Cin * 128;
    if (idx >= total) return;
    int co = idx & 127;
    int rest = idx >> 7;
    int ci = rest % Cin;
    int t = rest / Cin;
    wT[idx] = w[((size_t)co * Cin + ci) * 27 + t];
}

// ------------------------------------------------------------ direct 3x3x3 conv
// in  : [CB, R3, CIN]  channels-last (chunk-local)
// out : [CB, R3, 128]  channels-last (conv + bias), fused GN sum/sumsq stats
// block: one (bl,x,y) z-column; 256 thr = 128 co x 2 z-halves (16 z each)
template <int CIN>
__global__ void k_conv(const float* __restrict__ in, const float* __restrict__ wT,
                       const float* __restrict__ bias, float* __restrict__ out,
                       float* __restrict__ stats, int b0) {
    __shared__ __align__(16) float colbuf[34 * CIN];  // zp = z+1, zero halo rows 0 & 33
    __shared__ float s_sum[8], s_sq[8];
    int tid = threadIdx.x;
    int bid = blockIdx.x;
    int xy = bid & 1023, bl = bid >> 10;
    int x = xy >> 5, y = xy & 31;
    int co = tid & 127;
    int z0 = (tid >> 7) * 16;

    if (tid < CIN) { colbuf[tid] = 0.0f; colbuf[33 * CIN + tid] = 0.0f; }
    if (tid < 8) { s_sum[tid] = 0.0f; s_sq[tid] = 0.0f; }

    float acc[16];
    float bv = bias[co];
#pragma unroll
    for (int j = 0; j < 16; ++j) acc[j] = bv;

    const float4* ldsv = (const float4*)colbuf;
    for (int t9 = 0; t9 < 9; ++t9) {
        int dxi = t9 / 3, dyi = t9 % 3;
        int xx = x + dxi - 1, yy = y + dyi - 1;
        if (xx < 0 || xx >= R_ || yy < 0 || yy >= R_) continue;  // block-uniform
        __syncthreads();
        // stage full z-column (32*CIN contiguous floats) into rows 1..32
        const float4* src = (const float4*)(in + ((size_t)bl * R3_ + xx * 1024 + yy * 32) * CIN);
        float4* dst = (float4*)(colbuf + CIN);
        for (int i = tid; i < 32 * CIN / 4; i += 256) dst[i] = src[i];
        __syncthreads();

        for (int ci4 = 0; ci4 < CIN; ci4 += 4) {
            float w[3][4];
#pragma unroll
            for (int dz = 0; dz < 3; ++dz)
#pragma unroll
                for (int k = 0; k < 4; ++k)
                    w[dz][k] = wT[((size_t)((t9 * 3 + dz) * CIN + ci4 + k)) * 128 + co];
#pragma unroll
            for (int jb = 0; jb < 2; ++jb) {
                float4 v[10];
#pragma unroll
                for (int m = 0; m < 10; ++m)
                    v[m] = ldsv[(z0 + jb * 8 + m) * (CIN / 4) + (ci4 >> 2)];
#pragma unroll
                for (int jj = 0; jj < 8; ++jj) {
                    int j = jb * 8 + jj;
#pragma unroll
                    for (int dz = 0; dz < 3; ++dz) {
                        float4 vv = v[jj + dz];
                        acc[j] += vv.x * w[dz][0] + vv.y * w[dz][1] +
                                  vv.z * w[dz][2] + vv.w * w[dz][3];
                    }
                }
            }
        }
    }

    float* op = out + ((size_t)bl * R3_ + x * 1024 + y * 32 + z0) * 128 + co;
    float lsum = 0.f, lsq = 0.f;
#pragma unroll
    for (int j = 0; j < 16; ++j) {
        op[(size_t)j * 128] = acc[j];
        lsum += acc[j];
        lsq += acc[j] * acc[j];
    }
    int g = co >> 4;
    atomicAdd(&s_sum[g], lsum);
    atomicAdd(&s_sq[g], lsq);
    __syncthreads();
    if (tid < 8) {
        int b = b0 + bl;
        atomicAdd(&stats[((size_t)b * 8 + tid) * 2 + 0], s_sum[tid]);
        atomicAdd(&stats[((size_t)b * 8 + tid) * 2 + 1], s_sq[tid]);
    }
}

// --------------------------------------------------- GN finalize: per-(b,c) A,B
__global__ void k_finalize(const float* __restrict__ stats, const float* __restrict__ gamma,
                           const float* __restrict__ beta, float* __restrict__ ss, float count) {
    int idx = blockIdx.x * 256 + threadIdx.x;
    if (idx >= B_ * COUT_) return;
    int b = idx >> 7, c = idx & 127;
    int g = c >> 4;
    float sum = stats[(b * 8 + g) * 2 + 0], sq = stats[(b * 8 + g) * 2 + 1];
    float mean = sum / count;
    float var = sq / count - mean * mean;
    float inv = rsqrtf(var + EPS_);
    float A = gamma[c] * inv;
    float Bc = beta[c] - mean * A;
    ss[idx * 2 + 0] = A;
    ss[idx * 2 + 1] = Bc;
}

// ------------------------------------------- elementwise GN apply + swish (in-place)
__global__ void k_gnswish(float* __restrict__ grid, const float* __restrict__ ss, int b0) {
    size_t idx4 = (size_t)blockIdx.x * 256 + threadIdx.x;  // < CB*R3*32
    int c4 = (int)(idx4 & 31) * 4;
    int b = b0 + (int)(idx4 >> 20);
    float4* g = (float4*)grid;
    float4 v = g[idx4];
    const float* sp = ss + (size_t)(b * 128 + c4) * 2;
    float r[4] = {v.x, v.y, v.z, v.w};
#pragma unroll
    for (int k = 0; k < 4; ++k) {
        float s = sp[k * 2] * r[k] + sp[k * 2 + 1];
        r[k] = s / (1.0f + expf(-s));
    }
    g[idx4] = make_float4(r[0], r[1], r[2], r[3]);
}

// ------------------------------------------------ point transform 64->128 + stats
// pf region chunk-local: [CB, 128, N]
__global__ void k_point(const float* __restrict__ feat, const float* __restrict__ w,
                        const float* __restrict__ bias, float* __restrict__ pf,
                        float* __restrict__ stats, int b0) {
    int bid = blockIdx.x;  // CB * 128co * 16 chunks
    int nch = bid & 15, co = (bid >> 4) & 127, bl = bid >> 11;
    int b = b0 + bl;
    int n = nch * 256 + threadIdx.x;
    const float* f = feat + (size_t)b * CIN_ * N_ + n;
    const float* wr = w + co * CIN_;
    float acc = bias[co];
#pragma unroll 8
    for (int ci = 0; ci < CIN_; ++ci) acc += wr[ci] * f[(size_t)ci * N_];
    pf[((size_t)bl * 128 + co) * N_ + n] = acc;
    __shared__ float bs[2];
    if (threadIdx.x == 0) { bs[0] = 0.f; bs[1] = 0.f; }
    __syncthreads();
    atomicAdd(&bs[0], acc);
    atomicAdd(&bs[1], acc * acc);
    __syncthreads();
    if (threadIdx.x == 0) {
        int g = co >> 4;
        atomicAdd(&stats[((size_t)b * 8 + g) * 2 + 0], bs[0]);
        atomicAdd(&stats[((size_t)b * 8 + g) * 2 + 1], bs[1]);
    }
}

// -------------------------- trilinear devoxelize + point-branch GN/swish + add
// block: 128 threads (=co), per (bl, 32-point chunk)
__global__ void k_final(const float* __restrict__ grid, const float* __restrict__ ncoords,
                        const float* __restrict__ pf, const float* __restrict__ ss,
                        float* __restrict__ out, int b0) {
    __shared__ int sidx[32][8];
    __shared__ float swt[32][8];
    __shared__ __align__(16) float devt[32 * 128];
    int bid = blockIdx.x;
    int bl = bid >> 7;
    int b = b0 + bl;
    int n0 = (bid & 127) * 32;
    int tid = threadIdx.x;  // 0..127
    if (tid < 32) {
        int n = n0 + tid;
        const float* nc = ncoords + ((size_t)b * N_ + n) * 3;
        float fc[3] = {nc[0], nc[1], nc[2]};
        int i0[3], i1[3];
        float dd[3];
        for (int k = 0; k < 3; ++k) {
            float fl = floorf(fc[k]);
            i0[k] = (int)fl;
            i1[k] = min(i0[k] + 1, R_ - 1);
            dd[k] = fc[k] - fl;
        }
#pragma unroll
        for (int k = 0; k < 8; ++k) {
            int ix = (k >> 2) & 1, iy = (k >> 1) & 1, iz = k & 1;
            int xi = ix ? i1[0] : i0[0];
            int yi = iy ? i1[1] : i0[1];
            int zi = iz ? i1[2] : i0[2];
            sidx[tid][k] = (xi * R_ + yi) * R_ + zi;
            float wx = ix ? dd[0] : 1.0f - dd[0];
            float wy = iy ? dd[1] : 1.0f - dd[1];
            float wz = iz ? dd[2] : 1.0f - dd[2];
            swt[tid][k] = wx * wy * wz;
        }
    }
    __syncthreads();
    int co = tid;
    const float* g = grid + (size_t)bl * R3_ * 128 + co;
    for (int p = 0; p < 32; ++p) {
        float acc = 0.f;
#pragma unroll
        for (int k = 0; k < 8; ++k) acc += swt[p][k] * g[(size_t)sidx[p][k] * 128];
        devt[p * 128 + co] = acc;
    }
    __syncthreads();
    float A = ss[(b * 128 + co) * 2 + 0], Bc = ss[(b * 128 + co) * 2 + 1];
    const float* pfp = pf + ((size_t)bl * 128 + co) * N_ + n0;
    float* op = out + ((size_t)b * 128 + co) * N_ + n0;
    for (int j0 = 0; j0 < 32; j0 += 4) {
        float4 x4 = *(const float4*)(pfp + j0);
        float xr[4] = {x4.x, x4.y, x4.z, x4.w};
        float4 o4;
        float* orr = (float*)&o4;
#pragma unroll
        for (int k = 0; k < 4; ++k) {
            float s = A * xr[k] + Bc;
            float sw = s / (1.0f + expf(-s));
            orr[k] = devt[(j0 + k) * 128 + co] + sw;
        }
        *(float4*)(op + j0) = o4;
    }
}

extern "C" void kernel_launch(void* const* d_in, const int* in_sizes, int n_in,
                              void* d_out, int out_size, void* d_ws, size_t ws_size,
                              hipStream_t stream) {
    const float* features = (const float*)d_in[0];
    const float* coords = (const float*)d_in[1];
    const float* c1w = (const float*)d_in[2];
    const float* c1b = (const float*)d_in[3];
    const float* g1g = (const float*)d_in[4];
    const float* g1b = (const float*)d_in[5];
    const float* c2w = (const float*)d_in[6];
    const float* c2b = (const float*)d_in[7];
    const float* g2g = (const float*)d_in[8];
    const float* g2b = (const float*)d_in[9];
    const float* ptw = (const float*)d_in[10];
    const float* ptb = (const float*)d_in[11];
    const float* pgg = (const float*)d_in[12];
    const float* pgb = (const float*)d_in[13];
    float* outp = (float*)d_out;

    // ---- choose batch-chunk size CB so the workspace fits ws_size
    int CB = 1;
    size_t globals = ((size_t)B_ * R3_ * 4 + 255 & ~(size_t)255)       // cnt
                   + ((size_t)B_ * N_ * 3 * 4 + 255 & ~(size_t)255)    // ncoords
                   + ((size_t)B_ * N_ * 4 + 255 & ~(size_t)255)        // flatidx
                   + 256                                               // bstats
                   + 2048                                              // statsAll (pad)
                   + 3 * ((size_t)B_ * 128 * 2 * 4 + 255 & ~(size_t)255) // ss1/2/pt
                   + ((size_t)27 * 64 * 128 * 4 + 255 & ~(size_t)255)  // wT1
                   + ((size_t)27 * 128 * 128 * 4 + 255 & ~(size_t)255) // wT2
                   + 4096;                                             // slack
    for (int cb = 8; cb >= 1; cb >>= 1) {
        size_t need = globals
                    + 2 * ((size_t)cb * R3_ * 128 * 4)   // regA + regB
                    + ((size_t)cb * 128 * N_ * 4);       // pf
        if (need <= ws_size) { CB = cb; break; }
    }

    char* ws = (char*)d_ws;
    size_t o = 0;
    auto alloc = [&](size_t bytes) {
        size_t r = o;
        o += (bytes + 255) & ~(size_t)255;
        return r;
    };
    float* regA = (float*)(ws + alloc((size_t)CB * R3_ * 128 * 4));  // vox[.,64] then conv2 out
    float* regB = (float*)(ws + alloc((size_t)CB * R3_ * 128 * 4));  // conv1 out
    float* pfbuf = (float*)(ws + alloc((size_t)CB * 128 * N_ * 4));
    float* cnt = (float*)(ws + alloc((size_t)B_ * R3_ * 4));
    float* ncoords = (float*)(ws + alloc((size_t)B_ * N_ * 3 * 4));
    int* flatidx = (int*)(ws + alloc((size_t)B_ * N_ * 4));
    float* bstats = (float*)(ws + alloc(B_ * 4 * 4));
    float* statsAll = (float*)(ws + alloc(3 * 512));
    float* stats1 = statsAll;
    float* stats2 = statsAll + 128;
    float* statsPt = statsAll + 256;
    float* ss1 = (float*)(ws + alloc(B_ * 128 * 2 * 4));
    float* ss2 = (float*)(ws + alloc(B_ * 128 * 2 * 4));
    float* ssPt = (float*)(ws + alloc(B_ * 128 * 2 * 4));
    float* wT1 = (float*)(ws + alloc((size_t)27 * 64 * 128 * 4));
    float* wT2 = (float*)(ws + alloc((size_t)27 * 128 * 128 * 4));

    // ---- globals (once)
    hipMemsetAsync(cnt, 0, (size_t)B_ * R3_ * 4, stream);
    hipMemsetAsync(statsAll, 0, 3 * 512, stream);
    k_wtrans<<<(27 * 64 * 128 + 255) / 256, 256, 0, stream>>>(c1w, wT1, 64);
    k_wtrans<<<(27 * 128 * 128 + 255) / 256, 256, 0, stream>>>(c2w, wT2, 128);
    k_batch_stats<<<B_, 256, 0, stream>>>(coords, bstats);
    k_points<<<B_ * N_ / 256, 256, 0, stream>>>(coords, bstats, ncoords, flatidx, cnt);

    // ---- per batch-chunk pipeline (regions recycled)
    for (int b0 = 0; b0 < B_; b0 += CB) {
        hipMemsetAsync(regA, 0, (size_t)CB * R3_ * CIN_ * 4, stream);
        k_scatter<<<CB * 64 * 16, 256, 0, stream>>>(features, flatidx, regA, b0);
        k_divide<<<CB * R3_ * 16 / 256, 256, 0, stream>>>(regA, cnt, b0);
        k_conv<64><<<CB * 1024, 256, 0, stream>>>(regA, wT1, c1b, regB, stats1, b0);
        k_finalize<<<4, 256, 0, stream>>>(stats1, g1g, g1b, ss1, 16.0f * R3_);
        k_gnswish<<<CB * R3_ * 32 / 256, 256, 0, stream>>>(regB, ss1, b0);
        k_conv<128><<<CB * 1024, 256, 0, stream>>>(regB, wT2, c2b, regA, stats2, b0);
        k_finalize<<<4, 256, 0, stream>>>(stats2, g2g, g2b, ss2, 16.0f * R3_);
        k_gnswish<<<CB * R3_ * 32 / 256, 256, 0, stream>>>(regA, ss2, b0);
        k_point<<<CB * 128 * 16, 256, 0, stream>>>(features, ptw, ptb, pfbuf, statsPt, b0);
        k_finalize<<<4, 256, 0, stream>>>(statsPt, pgg, pgb, ssPt, 16.0f * N_);
        k_final<<<CB * 128, 128, 0, stream>>>(regA, ncoords, pfbuf, ssPt, outp, b0);
    }
}

// Round 3
// 930.233 us; speedup vs baseline: 7.3930x; 7.3930x over previous
//
#include <hip/hip_runtime.h>
#include <hip/hip_bf16.h>
#include <cstdint>

#define B_ 8
#define N_ 4096
#define CIN_ 64
#define COUT_ 128
#define R_ 32
#define R3_ 32768
#define GROUPS_ 8
#define EPS_ 1e-5f

typedef float f32x4 __attribute__((ext_vector_type(4)));
typedef __bf16 bf16x8 __attribute__((ext_vector_type(8)));
typedef unsigned short ushort8x __attribute__((ext_vector_type(8)));

static __device__ __forceinline__ unsigned short f2b(float f) {
    uint32_t u = __float_as_uint(f);
    uint32_t r = (u + 0x7fffu + ((u >> 16) & 1u)) >> 16;  // RNE
    return (unsigned short)r;
}
static __device__ __forceinline__ float b2f(unsigned short u) {
    return __uint_as_float(((uint32_t)u) << 16);
}

// ---------------------------------------------------------------- batch stats
__global__ void k_batch_stats(const float* __restrict__ coords, float* __restrict__ bstats) {
    int b = blockIdx.x;
    int tid = threadIdx.x;
    __shared__ float rb[256];
    __shared__ float smean[3];
    const float* cb = coords + (size_t)b * N_ * 3;
    float sx = 0.f, sy = 0.f, sz = 0.f;
    for (int n = tid; n < N_; n += 256) {
        sx += cb[n * 3 + 0];
        sy += cb[n * 3 + 1];
        sz += cb[n * 3 + 2];
    }
    float vals[3] = {sx, sy, sz};
    for (int k = 0; k < 3; ++k) {
        rb[tid] = vals[k];
        __syncthreads();
        for (int s = 128; s > 0; s >>= 1) {
            if (tid < s) rb[tid] += rb[tid + s];
            __syncthreads();
        }
        if (tid == 0) smean[k] = rb[0] / (float)N_;
        __syncthreads();
    }
    float mx = smean[0], my = smean[1], mz = smean[2];
    float m2 = 0.f;
    for (int n = tid; n < N_; n += 256) {
        float dx = cb[n * 3 + 0] - mx, dy = cb[n * 3 + 1] - my, dz = cb[n * 3 + 2] - mz;
        m2 = fmaxf(m2, dx * dx + dy * dy + dz * dz);
    }
    rb[tid] = m2;
    __syncthreads();
    for (int s = 128; s > 0; s >>= 1) {
        if (tid < s) rb[tid] = fmaxf(rb[tid], rb[tid + s]);
        __syncthreads();
    }
    if (tid == 0) {
        bstats[b * 4 + 0] = mx;
        bstats[b * 4 + 1] = my;
        bstats[b * 4 + 2] = mz;
        bstats[b * 4 + 3] = 2.0f * sqrtf(rb[0]);
    }
}

// -------------------------------------------------- per-point coords + counts
__global__ void k_points(const float* __restrict__ coords, const float* __restrict__ bstats,
                         float* __restrict__ ncoords, int* __restrict__ flatidx,
                         float* __restrict__ cnt) {
    int idx = blockIdx.x * 256 + threadIdx.x;  // b*N + n
    int b = idx >> 12, n = idx & (N_ - 1);
    float scale = bstats[b * 4 + 3];
    int vi[3];
    for (int k = 0; k < 3; ++k) {
        float c = coords[((size_t)b * N_ + n) * 3 + k] - bstats[b * 4 + k];
        float nc = fminf(fmaxf((c / scale + 0.5f) * (float)R_, 0.0f), (float)(R_ - 1));
        ncoords[((size_t)b * N_ + n) * 3 + k] = nc;
        vi[k] = (int)rintf(nc);  // round half-to-even, matches jnp.round
    }
    int flat = (vi[0] * R_ + vi[1]) * R_ + vi[2];
    flatidx[idx] = flat;
    atomicAdd(&cnt[(size_t)b * R3_ + flat], 1.0f);
}

// ------------------------------------------------------------- scatter (sum)
__global__ void k_scatter(const float* __restrict__ feat, const int* __restrict__ flatidx,
                          float* __restrict__ vox, int b0) {
    int bid = blockIdx.x;               // CB * 64ci * 16 chunks
    int nch = bid & 15, ci = (bid >> 4) & 63, bl = bid >> 10;
    int b = b0 + bl;
    int n = nch * 256 + threadIdx.x;
    float v = feat[((size_t)b * CIN_ + ci) * N_ + n];
    int flat = flatidx[b * N_ + n];
    atomicAdd(&vox[((size_t)bl * R3_ + flat) * CIN_ + ci], v);
}

// ----------------------------------- divide by counts, fp32 -> bf16 channels-last
__global__ void k_divide(const float* __restrict__ vox, const float* __restrict__ cnt,
                         unsigned short* __restrict__ gA, int b0) {
    size_t idx8 = (size_t)blockIdx.x * 256 + threadIdx.x;  // < cb*R3*8
    size_t voxel = idx8 >> 3;                              // bl*R3 + flat
    float c = cnt[(size_t)b0 * R3_ + voxel];
    float s = 1.0f / fmaxf(c, 1.0f);
    const float4* v4 = (const float4*)vox;
    float4 a = v4[idx8 * 2], b = v4[idx8 * 2 + 1];
    ushort8x o;
    o[0] = f2b(a.x * s); o[1] = f2b(a.y * s); o[2] = f2b(a.z * s); o[3] = f2b(a.w * s);
    o[4] = f2b(b.x * s); o[5] = f2b(b.y * s); o[6] = f2b(b.z * s); o[7] = f2b(b.w * s);
    ((ushort8x*)gA)[idx8] = o;
}

// ----------------------------------------- weight pack for MFMA B-fragments (bf16)
// wp element e = (((t*KC + kc)*8 + ct)*64 + l)*8 + j  holds
//   w[co = ct*16 + (l&15)][ci = kc*32 + (l>>4)*8 + j][t],  w layout [128][CIN][27]
__global__ void k_wpack(const float* __restrict__ w, unsigned short* __restrict__ wp, int Cin) {
    int e = blockIdx.x * 256 + threadIdx.x;
    int total = 27 * Cin * 128;
    if (e >= total) return;
    int KC = Cin / 32;
    int j = e & 7;
    int l = (e >> 3) & 63;
    int rest = e >> 9;
    int ct = rest & 7;
    int stepk = rest >> 3;  // t*KC + kc
    int kc = stepk % KC;
    int t = stepk / KC;
    int co = ct * 16 + (l & 15);
    int ci = kc * 32 + (l >> 4) * 8 + j;
    wp[e] = f2b(w[((size_t)co * Cin + ci) * 27 + t]);
}

// ----------------------------- implicit-GEMM 3x3x3 conv via bf16 MFMA 16x16x32
// in  : [cb, R3, CIN] bf16 channels-last; out: [cb, R3, 128] bf16; fused GN stats
// block: (bl, x, 4 y-columns) -> 4y x 32z x 128co. 4 waves = (y-pair, co-half).
template <int CIN>
__global__ __launch_bounds__(256) void k_conv_mfma(
    const unsigned short* __restrict__ in, const unsigned short* __restrict__ wp,
    const float* __restrict__ bias, unsigned short* __restrict__ out,
    float* __restrict__ stats, int b0) {
    constexpr int KC = CIN / 32;
    constexpr int S = CIN + 8;  // padded row stride (bf16 elems), 16B-aligned rows
    __shared__ unsigned short abuf[6 * 34 * S];
    __shared__ float s_sum[8], s_sq[8];
    int tid = threadIdx.x;
    int bid = blockIdx.x;
    int yg = bid & 7, x = (bid >> 3) & 31, bl = bid >> 8;
    int y0 = yg * 4;
    int lane = tid & 63, wv = tid >> 6;
    int yp = wv & 1, ch = wv >> 1;
    int mrow = lane & 15, quad = lane >> 4;

    if (tid < 8) { s_sum[tid] = 0.f; s_sq[tid] = 0.f; }
    // zero z-halo rows 0 and 33 for all 6 columns
    for (int i = tid; i < 6 * 2 * (CIN / 8); i += 256) {
        int cy = i / (2 * (CIN / 8));
        int r = i - cy * (2 * (CIN / 8));
        int hz = (r >= (CIN / 8)) ? 33 : 0;
        int c8 = r % (CIN / 8);
        ushort8x zz = {0, 0, 0, 0, 0, 0, 0, 0};
        *(ushort8x*)&abuf[(cy * 34 + hz) * S + c8 * 8] = zz;
    }

    float bv[4];
#pragma unroll
    for (int ct = 0; ct < 4; ++ct) bv[ct] = bias[ch * 64 + ct * 16 + mrow];
    f32x4 acc[2][2][4];
#pragma unroll
    for (int a = 0; a < 2; ++a)
#pragma unroll
        for (int zt = 0; zt < 2; ++zt)
#pragma unroll
            for (int ct = 0; ct < 4; ++ct) {
                acc[a][zt][ct][0] = bv[ct]; acc[a][zt][ct][1] = bv[ct];
                acc[a][zt][ct][2] = bv[ct]; acc[a][zt][ct][3] = bv[ct];
            }

    for (int xxi = 0; xxi < 3; ++xxi) {
        int xx = x + xxi - 1;
        if (xx < 0 || xx >= 32) continue;  // zero-pad: drop dx taps (block-uniform)
        __syncthreads();
        // stage 6 y-columns (32 z x CIN bf16 each) into rows 1..32
        for (int i = tid; i < 6 * 4 * CIN; i += 256) {  // 6*32*(CIN/8)
            int cy = i / (4 * CIN);
            int r = i - cy * (4 * CIN);
            int z = r / (CIN / 8), c8 = r - z * (CIN / 8);
            int yy = y0 - 1 + cy;
            ushort8x v = {0, 0, 0, 0, 0, 0, 0, 0};
            if (yy >= 0 && yy < 32)
                v = *(const ushort8x*)&in[((size_t)bl * R3_ + xx * 1024 + yy * 32 + z) * CIN + c8 * 8];
            *(ushort8x*)&abuf[(cy * 34 + z + 1) * S + c8 * 8] = v;
        }
        __syncthreads();

        for (int dy3 = 0; dy3 < 3; ++dy3) {
            for (int dz = 0; dz < 3; ++dz) {
#pragma unroll
                for (int kc = 0; kc < KC; ++kc) {
                    int t = (xxi * 3 + dy3) * 3 + dz;
                    const unsigned short* wbase =
                        wp + ((size_t)((t * KC + kc) * 8 + ch * 4) * 64 + lane) * 8;
                    bf16x8 bfr[4];
#pragma unroll
                    for (int ct = 0; ct < 4; ++ct)
                        bfr[ct] = *(const bf16x8*)(wbase + ct * 512);
#pragma unroll
                    for (int yo2 = 0; yo2 < 2; ++yo2) {
                        int cy = yp * 2 + yo2 + dy3;
#pragma unroll
                        for (int zt = 0; zt < 2; ++zt) {
                            bf16x8 a = *(const bf16x8*)
                                &abuf[(cy * 34 + zt * 16 + mrow + dz) * S + kc * 32 + quad * 8];
#pragma unroll
                            for (int ct = 0; ct < 4; ++ct)
                                acc[yo2][zt][ct] = __builtin_amdgcn_mfma_f32_16x16x32_bf16(
                                    a, bfr[ct], acc[yo2][zt][ct], 0, 0, 0);
                        }
                    }
                }
            }
        }
    }

    // store (bf16) + GN stats
    float lsum[4] = {0.f, 0.f, 0.f, 0.f}, lsq[4] = {0.f, 0.f, 0.f, 0.f};
#pragma unroll
    for (int yo2 = 0; yo2 < 2; ++yo2) {
        int y = y0 + yp * 2 + yo2;
#pragma unroll
        for (int zt = 0; zt < 2; ++zt) {
#pragma unroll
            for (int ct = 0; ct < 4; ++ct) {
                int co = ch * 64 + ct * 16 + mrow;
#pragma unroll
                for (int r = 0; r < 4; ++r) {
                    int z = zt * 16 + quad * 4 + r;
                    float vv = acc[yo2][zt][ct][r];
                    out[((size_t)bl * R3_ + x * 1024 + y * 32 + z) * 128 + co] = f2b(vv);
                    lsum[ct] += vv;
                    lsq[ct] += vv * vv;
                }
            }
        }
    }
#pragma unroll
    for (int ct = 0; ct < 4; ++ct) {
        atomicAdd(&s_sum[ch * 4 + ct], lsum[ct]);
        atomicAdd(&s_sq[ch * 4 + ct], lsq[ct]);
    }
    __syncthreads();
    if (tid < 8) {
        int b = b0 + bl;
        atomicAdd(&stats[((size_t)b * 8 + tid) * 2 + 0], s_sum[tid]);
        atomicAdd(&stats[((size_t)b * 8 + tid) * 2 + 1], s_sq[tid]);
    }
}

// --------------------------------------------------- GN finalize: per-(b,c) A,B
__global__ void k_finalize(const float* __restrict__ stats, const float* __restrict__ gamma,
                           const float* __restrict__ beta, float* __restrict__ ss, float count) {
    int idx = blockIdx.x * 256 + threadIdx.x;
    if (idx >= B_ * COUT_) return;
    int b = idx >> 7, c = idx & 127;
    int g = c >> 4;
    float sum = stats[(b * 8 + g) * 2 + 0], sq = stats[(b * 8 + g) * 2 + 1];
    float mean = sum / count;
    float var = sq / count - mean * mean;
    float inv = rsqrtf(var + EPS_);
    float A = gamma[c] * inv;
    float Bc = beta[c] - mean * A;
    ss[idx * 2 + 0] = A;
    ss[idx * 2 + 1] = Bc;
}

// ------------------------------- GN apply + swish, in-place on bf16 grid
__global__ void k_gnswish(unsigned short* __restrict__ g, const float* __restrict__ ss, int b0) {
    size_t idx8 = (size_t)blockIdx.x * 256 + threadIdx.x;  // < cb*R3*16
    int c0 = (int)(idx8 & 15) * 8;
    int b = b0 + (int)(idx8 >> 19);  // R3*128/8 = 2^19
    ushort8x v = ((ushort8x*)g)[idx8];
    const float* sp = ss + (size_t)(b * 128 + c0) * 2;
#pragma unroll
    for (int k = 0; k < 8; ++k) {
        float x = b2f(v[k]);
        float s = sp[k * 2] * x + sp[k * 2 + 1];
        v[k] = f2b(s / (1.0f + expf(-s)));
    }
    ((ushort8x*)g)[idx8] = v;
}

// ------------------------------------------------ point transform 64->128 + stats
__global__ void k_point(const float* __restrict__ feat, const float* __restrict__ w,
                        const float* __restrict__ bias, float* __restrict__ pf,
                        float* __restrict__ stats, int b0) {
    int bid = blockIdx.x;  // cb * 128co * 16 chunks
    int nch = bid & 15, co = (bid >> 4) & 127, bl = bid >> 11;
    int b = b0 + bl;
    int n = nch * 256 + threadIdx.x;
    const float* f = feat + (size_t)b * CIN_ * N_ + n;
    const float* wr = w + co * CIN_;
    float acc = bias[co];
#pragma unroll 8
    for (int ci = 0; ci < CIN_; ++ci) acc += wr[ci] * f[(size_t)ci * N_];
    pf[((size_t)bl * 128 + co) * N_ + n] = acc;
    __shared__ float bs[2];
    if (threadIdx.x == 0) { bs[0] = 0.f; bs[1] = 0.f; }
    __syncthreads();
    atomicAdd(&bs[0], acc);
    atomicAdd(&bs[1], acc * acc);
    __syncthreads();
    if (threadIdx.x == 0) {
        int g = co >> 4;
        atomicAdd(&stats[((size_t)b * 8 + g) * 2 + 0], bs[0]);
        atomicAdd(&stats[((size_t)b * 8 + g) * 2 + 1], bs[1]);
    }
}

// -------------------------- trilinear devoxelize + point-branch GN/swish + add
__global__ void k_final(const unsigned short* __restrict__ grid, const float* __restrict__ ncoords,
                        const float* __restrict__ pf, const float* __restrict__ ss,
                        float* __restrict__ out, int b0) {
    __shared__ int sidx[32][8];
    __shared__ float swt[32][8];
    __shared__ __align__(16) float devt[32 * 128];
    int bid = blockIdx.x;
    int bl = bid >> 7;
    int b = b0 + bl;
    int n0 = (bid & 127) * 32;
    int tid = threadIdx.x;  // 0..127
    if (tid < 32) {
        int n = n0 + tid;
        const float* nc = ncoords + ((size_t)b * N_ + n) * 3;
        float fc[3] = {nc[0], nc[1], nc[2]};
        int i0[3], i1[3];
        float dd[3];
        for (int k = 0; k < 3; ++k) {
            float fl = floorf(fc[k]);
            i0[k] = (int)fl;
            i1[k] = min(i0[k] + 1, R_ - 1);
            dd[k] = fc[k] - fl;
        }
#pragma unroll
        for (int k = 0; k < 8; ++k) {
            int ix = (k >> 2) & 1, iy = (k >> 1) & 1, iz = k & 1;
            int xi = ix ? i1[0] : i0[0];
            int yi = iy ? i1[1] : i0[1];
            int zi = iz ? i1[2] : i0[2];
            sidx[tid][k] = (xi * R_ + yi) * R_ + zi;
            float wx = ix ? dd[0] : 1.0f - dd[0];
            float wy = iy ? dd[1] : 1.0f - dd[1];
            float wz = iz ? dd[2] : 1.0f - dd[2];
            swt[tid][k] = wx * wy * wz;
        }
    }
    __syncthreads();
    int co = tid;
    const unsigned short* g = grid + (size_t)bl * R3_ * 128 + co;
    for (int p = 0; p < 32; ++p) {
        float acc = 0.f;
#pragma unroll
        for (int k = 0; k < 8; ++k) acc += swt[p][k] * b2f(g[(size_t)sidx[p][k] * 128]);
        devt[p * 128 + co] = acc;
    }
    __syncthreads();
    float A = ss[(b * 128 + co) * 2 + 0], Bc = ss[(b * 128 + co) * 2 + 1];
    const float* pfp = pf + ((size_t)bl * 128 + co) * N_ + n0;
    float* op = out + ((size_t)b * 128 + co) * N_ + n0;
    for (int j0 = 0; j0 < 32; j0 += 4) {
        float4 x4 = *(const float4*)(pfp + j0);
        float xr[4] = {x4.x, x4.y, x4.z, x4.w};
        float4 o4;
        float* orr = (float*)&o4;
#pragma unroll
        for (int k = 0; k < 4; ++k) {
            float s = A * xr[k] + Bc;
            float sw = s / (1.0f + expf(-s));
            orr[k] = devt[(j0 + k) * 128 + co] + sw;
        }
        *(float4*)(op + j0) = o4;
    }
}

extern "C" void kernel_launch(void* const* d_in, const int* in_sizes, int n_in,
                              void* d_out, int out_size, void* d_ws, size_t ws_size,
                              hipStream_t stream) {
    const float* features = (const float*)d_in[0];
    const float* coords = (const float*)d_in[1];
    const float* c1w = (const float*)d_in[2];
    const float* c1b = (const float*)d_in[3];
    const float* g1g = (const float*)d_in[4];
    const float* g1b = (const float*)d_in[5];
    const float* c2w = (const float*)d_in[6];
    const float* c2b = (const float*)d_in[7];
    const float* g2g = (const float*)d_in[8];
    const float* g2b = (const float*)d_in[9];
    const float* ptw = (const float*)d_in[10];
    const float* ptb = (const float*)d_in[11];
    const float* pgg = (const float*)d_in[12];
    const float* pgb = (const float*)d_in[13];
    float* outp = (float*)d_out;

    // sizes per chunk of cb batches:
    //   voxC : cb*R3*64*4  == cb*R3*128*2  (fp32 voxel accum, later conv2 bf16 out)
    //   gA   : cb*R3*64*2   (bf16 conv1 input)
    //   gB   : cb*R3*128*2  (bf16 conv1 output)
    //   pf   : cb*128*N*4
    size_t globals = ((size_t)B_ * R3_ * 4 + 255 & ~(size_t)255)        // cnt
                   + ((size_t)B_ * N_ * 3 * 4 + 255 & ~(size_t)255)     // ncoords
                   + ((size_t)B_ * N_ * 4 + 255 & ~(size_t)255)         // flatidx
                   + 256 + 2048                                         // bstats, statsAll
                   + 3 * ((size_t)B_ * 128 * 2 * 4 + 255 & ~(size_t)255)// ss1/2/pt
                   + ((size_t)27 * 64 * 128 * 2 + 255 & ~(size_t)255)   // wpack1
                   + ((size_t)27 * 128 * 128 * 2 + 255 & ~(size_t)255)  // wpack2
                   + 8192;                                              // slack
    int CB = 1;
    for (int cb = 8; cb >= 1; cb >>= 1) {
        size_t need = globals
                    + ((size_t)cb * R3_ * 64 * 4)     // voxC
                    + ((size_t)cb * R3_ * 64 * 2)     // gA
                    + ((size_t)cb * R3_ * 128 * 2)    // gB
                    + ((size_t)cb * 128 * N_ * 4);    // pf
        if (need <= ws_size) { CB = cb; break; }
    }

    char* ws = (char*)d_ws;
    size_t o = 0;
    auto alloc = [&](size_t bytes) {
        size_t r = o;
        o += (bytes + 255) & ~(size_t)255;
        return r;
    };
    float* voxC = (float*)(ws + alloc((size_t)CB * R3_ * 64 * 4));         // also gC bf16
    unsigned short* gC = (unsigned short*)voxC;
    unsigned short* gA = (unsigned short*)(ws + alloc((size_t)CB * R3_ * 64 * 2));
    unsigned short* gB = (unsigned short*)(ws + alloc((size_t)CB * R3_ * 128 * 2));
    float* pfbuf = (float*)(ws + alloc((size_t)CB * 128 * N_ * 4));
    float* cnt = (float*)(ws + alloc((size_t)B_ * R3_ * 4));
    float* ncoords = (float*)(ws + alloc((size_t)B_ * N_ * 3 * 4));
    int* flatidx = (int*)(ws + alloc((size_t)B_ * N_ * 4));
    float* bstats = (float*)(ws + alloc(256));
    float* statsAll = (float*)(ws + alloc(2048));
    float* stats1 = statsAll;
    float* stats2 = statsAll + 128;
    float* statsPt = statsAll + 256;
    float* ss1 = (float*)(ws + alloc(B_ * 128 * 2 * 4));
    float* ss2 = (float*)(ws + alloc(B_ * 128 * 2 * 4));
    float* ssPt = (float*)(ws + alloc(B_ * 128 * 2 * 4));
    unsigned short* wp1 = (unsigned short*)(ws + alloc((size_t)27 * 64 * 128 * 2));
    unsigned short* wp2 = (unsigned short*)(ws + alloc((size_t)27 * 128 * 128 * 2));

    // ---- globals (once per launch)
    hipMemsetAsync(cnt, 0, (size_t)B_ * R3_ * 4, stream);
    hipMemsetAsync(statsAll, 0, 1536, stream);
    k_wpack<<<(27 * 64 * 128 + 255) / 256, 256, 0, stream>>>(c1w, wp1, 64);
    k_wpack<<<(27 * 128 * 128 + 255) / 256, 256, 0, stream>>>(c2w, wp2, 128);
    k_batch_stats<<<B_, 256, 0, stream>>>(coords, bstats);
    k_points<<<B_ * N_ / 256, 256, 0, stream>>>(coords, bstats, ncoords, flatidx, cnt);

    // ---- per batch-chunk pipeline
    for (int b0 = 0; b0 < B_; b0 += CB) {
        hipMemsetAsync(voxC, 0, (size_t)CB * R3_ * 64 * 4, stream);
        k_scatter<<<CB * 64 * 16, 256, 0, stream>>>(features, flatidx, voxC, b0);
        k_divide<<<CB * 1024, 256, 0, stream>>>(voxC, cnt, gA, b0);
        k_conv_mfma<64><<<CB * 256, 256, 0, stream>>>(gA, wp1, c1b, gB, stats1, b0);
        k_finalize<<<4, 256, 0, stream>>>(stats1, g1g, g1b, ss1, 16.0f * R3_);
        k_gnswish<<<CB * 2048, 256, 0, stream>>>(gB, ss1, b0);
        k_conv_mfma<128><<<CB * 256, 256, 0, stream>>>(gB, wp2, c2b, gC, stats2, b0);
        k_finalize<<<4, 256, 0, stream>>>(stats2, g2g, g2b, ss2, 16.0f * R3_);
        k_gnswish<<<CB * 2048, 256, 0, stream>>>(gC, ss2, b0);
        k_point<<<CB * 128 * 16, 256, 0, stream>>>(features, ptw, ptb, pfbuf, statsPt, b0);
        k_finalize<<<4, 256, 0, stream>>>(statsPt, pgg, pgb, ssPt, 16.0f * N_);
        k_final<<<CB * 128, 128, 0, stream>>>(gC, ncoords, pfbuf, ssPt, outp, b0);
    }
}

// Round 4
// 701.363 us; speedup vs baseline: 9.8055x; 1.3263x over previous
//
#include <hip/hip_runtime.h>
#include <hip/hip_bf16.h>
#include <cstdint>

#define B_ 8
#define N_ 4096
#define CIN_ 64
#define COUT_ 128
#define R_ 32
#define R3_ 32768
#define GROUPS_ 8
#define EPS_ 1e-5f

typedef float f32x4 __attribute__((ext_vector_type(4)));
typedef __bf16 bf16x8 __attribute__((ext_vector_type(8)));
typedef unsigned short ushort8x __attribute__((ext_vector_type(8)));

static __device__ __forceinline__ unsigned short f2b(float f) {
    uint32_t u = __float_as_uint(f);
    uint32_t r = (u + 0x7fffu + ((u >> 16) & 1u)) >> 16;  // RNE
    return (unsigned short)r;
}
static __device__ __forceinline__ float b2f(unsigned short u) {
    return __uint_as_float(((uint32_t)u) << 16);
}

// ---------------------------------------------------------------- batch stats
__global__ void k_batch_stats(const float* __restrict__ coords, float* __restrict__ bstats) {
    int b = blockIdx.x;
    int tid = threadIdx.x;
    __shared__ float rb[256];
    __shared__ float smean[3];
    const float* cb = coords + (size_t)b * N_ * 3;
    float sx = 0.f, sy = 0.f, sz = 0.f;
    for (int n = tid; n < N_; n += 256) {
        sx += cb[n * 3 + 0];
        sy += cb[n * 3 + 1];
        sz += cb[n * 3 + 2];
    }
    float vals[3] = {sx, sy, sz};
    for (int k = 0; k < 3; ++k) {
        rb[tid] = vals[k];
        __syncthreads();
        for (int s = 128; s > 0; s >>= 1) {
            if (tid < s) rb[tid] += rb[tid + s];
            __syncthreads();
        }
        if (tid == 0) smean[k] = rb[0] / (float)N_;
        __syncthreads();
    }
    float mx = smean[0], my = smean[1], mz = smean[2];
    float m2 = 0.f;
    for (int n = tid; n < N_; n += 256) {
        float dx = cb[n * 3 + 0] - mx, dy = cb[n * 3 + 1] - my, dz = cb[n * 3 + 2] - mz;
        m2 = fmaxf(m2, dx * dx + dy * dy + dz * dz);
    }
    rb[tid] = m2;
    __syncthreads();
    for (int s = 128; s > 0; s >>= 1) {
        if (tid < s) rb[tid] = fmaxf(rb[tid], rb[tid + s]);
        __syncthreads();
    }
    if (tid == 0) {
        bstats[b * 4 + 0] = mx;
        bstats[b * 4 + 1] = my;
        bstats[b * 4 + 2] = mz;
        bstats[b * 4 + 3] = 2.0f * sqrtf(rb[0]);
    }
}

// -------------------------------------------------- per-point coords + counts
__global__ void k_points(const float* __restrict__ coords, const float* __restrict__ bstats,
                         float* __restrict__ ncoords, int* __restrict__ flatidx,
                         float* __restrict__ cnt) {
    int idx = blockIdx.x * 256 + threadIdx.x;  // b*N + n
    int b = idx >> 12, n = idx & (N_ - 1);
    float scale = bstats[b * 4 + 3];
    int vi[3];
    for (int k = 0; k < 3; ++k) {
        float c = coords[((size_t)b * N_ + n) * 3 + k] - bstats[b * 4 + k];
        float nc = fminf(fmaxf((c / scale + 0.5f) * (float)R_, 0.0f), (float)(R_ - 1));
        ncoords[((size_t)b * N_ + n) * 3 + k] = nc;
        vi[k] = (int)rintf(nc);  // round half-to-even, matches jnp.round
    }
    int flat = (vi[0] * R_ + vi[1]) * R_ + vi[2];
    flatidx[idx] = flat;
    atomicAdd(&cnt[(size_t)b * R3_ + flat], 1.0f);
}

// ------------------------------------------------------------- scatter (sum)
__global__ void k_scatter(const float* __restrict__ feat, const int* __restrict__ flatidx,
                          float* __restrict__ vox, int b0) {
    int bid = blockIdx.x;               // CB * 64ci * 16 chunks
    int nch = bid & 15, ci = (bid >> 4) & 63, bl = bid >> 10;
    int b = b0 + bl;
    int n = nch * 256 + threadIdx.x;
    float v = feat[((size_t)b * CIN_ + ci) * N_ + n];
    int flat = flatidx[b * N_ + n];
    atomicAdd(&vox[((size_t)bl * R3_ + flat) * CIN_ + ci], v);
}

// ----------------------------------- divide by counts, fp32 -> bf16 channels-last
__global__ void k_divide(const float* __restrict__ vox, const float* __restrict__ cnt,
                         unsigned short* __restrict__ gA, int b0) {
    size_t idx8 = (size_t)blockIdx.x * 256 + threadIdx.x;  // < cb*R3*8
    size_t voxel = idx8 >> 3;                              // bl*R3 + flat
    float c = cnt[(size_t)b0 * R3_ + voxel];
    float s = 1.0f / fmaxf(c, 1.0f);
    const float4* v4 = (const float4*)vox;
    float4 a = v4[idx8 * 2], b = v4[idx8 * 2 + 1];
    ushort8x o;
    o[0] = f2b(a.x * s); o[1] = f2b(a.y * s); o[2] = f2b(a.z * s); o[3] = f2b(a.w * s);
    o[4] = f2b(b.x * s); o[5] = f2b(b.y * s); o[6] = f2b(b.z * s); o[7] = f2b(b.w * s);
    ((ushort8x*)gA)[idx8] = o;
}

// ---------------------------------------- features fp32 -> bf16 (chunk-local)
__global__ void k_feat2b(const float* __restrict__ f, unsigned short* __restrict__ fb, int b0) {
    size_t i8 = (size_t)blockIdx.x * 256 + threadIdx.x;  // < CB*64*N/8
    const float4* s = (const float4*)(f + (size_t)b0 * CIN_ * N_);
    float4 a = s[i8 * 2], b = s[i8 * 2 + 1];
    ushort8x o;
    o[0] = f2b(a.x); o[1] = f2b(a.y); o[2] = f2b(a.z); o[3] = f2b(a.w);
    o[4] = f2b(b.x); o[5] = f2b(b.y); o[6] = f2b(b.z); o[7] = f2b(b.w);
    ((ushort8x*)fb)[i8] = o;
}

// ----------------------------------------- weight pack for MFMA B-fragments (bf16)
// wp element e = (((t*KC + kc)*8 + ct)*64 + l)*8 + j  holds
//   w[co = ct*16 + (l&15)][ci = kc*32 + (l>>4)*8 + j][t],  w layout [128][Cin][taps]
__global__ void k_wpack(const float* __restrict__ w, unsigned short* __restrict__ wp,
                        int Cin, int taps) {
    int e = blockIdx.x * 256 + threadIdx.x;
    int total = taps * Cin * 128;
    if (e >= total) return;
    int KC = Cin / 32;
    int j = e & 7;
    int l = (e >> 3) & 63;
    int rest = e >> 9;
    int ct = rest & 7;
    int stepk = rest >> 3;  // t*KC + kc
    int kc = stepk % KC;
    int t = stepk / KC;
    int co = ct * 16 + (l & 15);
    int ci = kc * 32 + (l >> 4) * 8 + j;
    wp[e] = f2b(w[((size_t)co * Cin + ci) * taps + t]);
}

// ----------------------------- implicit-GEMM 3x3x3 conv via bf16 MFMA 16x16x32
// in  : [cb, R3, CIN] bf16 channels-last; out: [cb, R3, 128] bf16; fused GN stats
// block: (bl, x, 4 y-columns) -> 4y x 32z x 128co. 4 waves = (y-pair, co-half).
template <int CIN>
__global__ __launch_bounds__(256) void k_conv_mfma(
    const unsigned short* __restrict__ in, const unsigned short* __restrict__ wp,
    const float* __restrict__ bias, unsigned short* __restrict__ out,
    float* __restrict__ stats, int b0) {
    constexpr int KC = CIN / 32;
    constexpr int S = CIN + 8;  // padded row stride (bf16 elems), 16B-aligned rows
    __shared__ unsigned short abuf[6 * 34 * S];
    __shared__ float s_sum[8], s_sq[8];
    int tid = threadIdx.x;
    int bid = blockIdx.x;
    int yg = bid & 7, x = (bid >> 3) & 31, bl = bid >> 8;
    int y0 = yg * 4;
    int lane = tid & 63, wv = tid >> 6;
    int yp = wv & 1, ch = wv >> 1;
    int mrow = lane & 15, quad = lane >> 4;

    if (tid < 8) { s_sum[tid] = 0.f; s_sq[tid] = 0.f; }
    // zero z-halo rows 0 and 33 for all 6 columns
    for (int i = tid; i < 6 * 2 * (CIN / 8); i += 256) {
        int cy = i / (2 * (CIN / 8));
        int r = i - cy * (2 * (CIN / 8));
        int hz = (r >= (CIN / 8)) ? 33 : 0;
        int c8 = r % (CIN / 8);
        ushort8x zz = {0, 0, 0, 0, 0, 0, 0, 0};
        *(ushort8x*)&abuf[(cy * 34 + hz) * S + c8 * 8] = zz;
    }

    float bv[4];
#pragma unroll
    for (int ct = 0; ct < 4; ++ct) bv[ct] = bias[ch * 64 + ct * 16 + mrow];
    f32x4 acc[2][2][4];
#pragma unroll
    for (int a = 0; a < 2; ++a)
#pragma unroll
        for (int zt = 0; zt < 2; ++zt)
#pragma unroll
            for (int ct = 0; ct < 4; ++ct) {
                acc[a][zt][ct][0] = bv[ct]; acc[a][zt][ct][1] = bv[ct];
                acc[a][zt][ct][2] = bv[ct]; acc[a][zt][ct][3] = bv[ct];
            }

    for (int xxi = 0; xxi < 3; ++xxi) {
        int xx = x + xxi - 1;
        if (xx < 0 || xx >= 32) continue;  // zero-pad: drop dx taps (block-uniform)
        __syncthreads();
        // stage 6 y-columns (32 z x CIN bf16 each) into rows 1..32
        for (int i = tid; i < 6 * 4 * CIN; i += 256) {  // 6*32*(CIN/8)
            int cy = i / (4 * CIN);
            int r = i - cy * (4 * CIN);
            int z = r / (CIN / 8), c8 = r - z * (CIN / 8);
            int yy = y0 - 1 + cy;
            ushort8x v = {0, 0, 0, 0, 0, 0, 0, 0};
            if (yy >= 0 && yy < 32)
                v = *(const ushort8x*)&in[((size_t)bl * R3_ + xx * 1024 + yy * 32 + z) * CIN + c8 * 8];
            *(ushort8x*)&abuf[(cy * 34 + z + 1) * S + c8 * 8] = v;
        }
        __syncthreads();

        for (int dy3 = 0; dy3 < 3; ++dy3) {
            for (int dz = 0; dz < 3; ++dz) {
#pragma unroll
                for (int kc = 0; kc < KC; ++kc) {
                    int t = (xxi * 3 + dy3) * 3 + dz;
                    const unsigned short* wbase =
                        wp + ((size_t)((t * KC + kc) * 8 + ch * 4) * 64 + lane) * 8;
                    bf16x8 bfr[4];
#pragma unroll
                    for (int ct = 0; ct < 4; ++ct)
                        bfr[ct] = *(const bf16x8*)(wbase + ct * 512);
#pragma unroll
                    for (int yo2 = 0; yo2 < 2; ++yo2) {
                        int cy = yp * 2 + yo2 + dy3;
#pragma unroll
                        for (int zt = 0; zt < 2; ++zt) {
                            bf16x8 a = *(const bf16x8*)
                                &abuf[(cy * 34 + zt * 16 + mrow + dz) * S + kc * 32 + quad * 8];
#pragma unroll
                            for (int ct = 0; ct < 4; ++ct)
                                acc[yo2][zt][ct] = __builtin_amdgcn_mfma_f32_16x16x32_bf16(
                                    a, bfr[ct], acc[yo2][zt][ct], 0, 0, 0);
                        }
                    }
                }
            }
        }
    }

    // store (bf16) + GN stats
    float lsum[4] = {0.f, 0.f, 0.f, 0.f}, lsq[4] = {0.f, 0.f, 0.f, 0.f};
#pragma unroll
    for (int yo2 = 0; yo2 < 2; ++yo2) {
        int y = y0 + yp * 2 + yo2;
#pragma unroll
        for (int zt = 0; zt < 2; ++zt) {
#pragma unroll
            for (int ct = 0; ct < 4; ++ct) {
                int co = ch * 64 + ct * 16 + mrow;
#pragma unroll
                for (int r = 0; r < 4; ++r) {
                    int z = zt * 16 + quad * 4 + r;
                    float vv = acc[yo2][zt][ct][r];
                    out[((size_t)bl * R3_ + x * 1024 + y * 32 + z) * 128 + co] = f2b(vv);
                    lsum[ct] += vv;
                    lsq[ct] += vv * vv;
                }
            }
        }
    }
#pragma unroll
    for (int ct = 0; ct < 4; ++ct) {
        atomicAdd(&s_sum[ch * 4 + ct], lsum[ct]);
        atomicAdd(&s_sq[ch * 4 + ct], lsq[ct]);
    }
    __syncthreads();
    if (tid < 8) {
        int b = b0 + bl;
        atomicAdd(&stats[((size_t)b * 8 + tid) * 2 + 0], s_sum[tid]);
        atomicAdd(&stats[((size_t)b * 8 + tid) * 2 + 1], s_sq[tid]);
    }
}

// --------------- GN apply + swish in-place on bf16 grid, A/B from raw stats
__global__ void k_gnswish(unsigned short* __restrict__ g, const float* __restrict__ stats,
                          const float* __restrict__ gamma, const float* __restrict__ beta,
                          int b0) {
    size_t idx8 = (size_t)blockIdx.x * 256 + threadIdx.x;  // < cb*R3*16
    int c0 = (int)(idx8 & 15) * 8;
    int b = b0 + (int)(idx8 >> 19);  // R3*128/8 = 2^19
    int grp = c0 >> 4;
    const float cntv = 16.0f * R3_;
    float mean = stats[(b * 8 + grp) * 2 + 0] / cntv;
    float var = stats[(b * 8 + grp) * 2 + 1] / cntv - mean * mean;
    float inv = rsqrtf(var + EPS_);
    ushort8x v = ((ushort8x*)g)[idx8];
#pragma unroll
    for (int k = 0; k < 8; ++k) {
        float A = gamma[c0 + k] * inv;
        float Bc = beta[c0 + k] - mean * A;
        float x = b2f(v[k]);
        float s = A * x + Bc;
        v[k] = f2b(s / (1.0f + expf(-s)));
    }
    ((ushort8x*)g)[idx8] = v;
}

// ------------------- point transform 64->128 via MFMA, pf bf16 [n][co], + stats
// block: (bl, 256-n tile); 4 waves = (n-half, co-half). M=n, N=co, K=64.
__global__ __launch_bounds__(256) void k_point_mfma(
    const unsigned short* __restrict__ featb, const unsigned short* __restrict__ wp,
    const float* __restrict__ bias, unsigned short* __restrict__ pf,
    float* __restrict__ stats, int b0) {
    __shared__ __align__(16) unsigned short ALds[256 * 72];  // [n][ci], stride 72 (144B rows)
    int tid = threadIdx.x;
    int bid = blockIdx.x;
    int bl = bid >> 4;
    int n0 = (bid & 15) * 256;
    int b = b0 + bl;
    int lane = tid & 63, wv = tid >> 6;
    int nh = wv & 1, ch = wv >> 1;
    int mrow = lane & 15, quad = lane >> 4;

    // stage + transpose: ALds[n][ci] from featb[bl][ci][n0+n]
    {
        int c0 = (tid >> 5) * 8;   // 8 ci per thread
        int nl = tid & 31;
        for (int u = 0; u < 8; ++u) {
            int n = u * 32 + nl;
            ushort8x v;
#pragma unroll
            for (int k = 0; k < 8; ++k)
                v[k] = featb[((size_t)(bl * 64 + c0 + k)) * N_ + n0 + n];
            *(ushort8x*)&ALds[n * 72 + c0] = v;
        }
    }

    // B fragments (weights) from packed global
    bf16x8 bfr[2][4];
#pragma unroll
    for (int kc = 0; kc < 2; ++kc)
#pragma unroll
        for (int ct = 0; ct < 4; ++ct)
            bfr[kc][ct] = *(const bf16x8*)&wp[((size_t)((kc * 8) + ch * 4 + ct) * 64 + lane) * 8];

    float bv[4];
#pragma unroll
    for (int ct = 0; ct < 4; ++ct) bv[ct] = bias[ch * 64 + ct * 16 + mrow];
    f32x4 acc[8][4];
#pragma unroll
    for (int mt = 0; mt < 8; ++mt)
#pragma unroll
        for (int ct = 0; ct < 4; ++ct) {
            acc[mt][ct][0] = bv[ct]; acc[mt][ct][1] = bv[ct];
            acc[mt][ct][2] = bv[ct]; acc[mt][ct][3] = bv[ct];
        }

    __syncthreads();
#pragma unroll
    for (int kc = 0; kc < 2; ++kc) {
#pragma unroll
        for (int mt = 0; mt < 8; ++mt) {
            bf16x8 a = *(const bf16x8*)
                &ALds[(nh * 128 + mt * 16 + mrow) * 72 + kc * 32 + quad * 8];
#pragma unroll
            for (int ct = 0; ct < 4; ++ct)
                acc[mt][ct] = __builtin_amdgcn_mfma_f32_16x16x32_bf16(
                    a, bfr[kc][ct], acc[mt][ct], 0, 0, 0);
        }
    }

    // store pf bf16 [n][co] + GN stats (wave-reduce: whole wave is one group per ct)
#pragma unroll
    for (int ct = 0; ct < 4; ++ct) {
        int co = ch * 64 + ct * 16 + mrow;
        float s = 0.f, q = 0.f;
#pragma unroll
        for (int mt = 0; mt < 8; ++mt) {
#pragma unroll
            for (int r = 0; r < 4; ++r) {
                int n = nh * 128 + mt * 16 + quad * 4 + r;
                float vv = acc[mt][ct][r];
                pf[((size_t)bl * N_ + n0 + n) * 128 + co] = f2b(vv);
                s += vv;
                q += vv * vv;
            }
        }
#pragma unroll
        for (int off = 32; off >= 1; off >>= 1) {
            s += __shfl_xor(s, off);
            q += __shfl_xor(q, off);
        }
        if (lane == 0) {
            int g = ch * 4 + ct;
            atomicAdd(&stats[((size_t)b * 8 + g) * 2 + 0], s);
            atomicAdd(&stats[((size_t)b * 8 + g) * 2 + 1], q);
        }
    }
}

// -------------------------- trilinear devoxelize + point-branch GN/swish + add
// block: 256 threads (2 point-groups x 128 co) per (bl, 32-point chunk)
__global__ __launch_bounds__(256) void k_final(
    const unsigned short* __restrict__ grid, const float* __restrict__ ncoords,
    const unsigned short* __restrict__ pf, const float* __restrict__ stats,
    const float* __restrict__ gamma, const float* __restrict__ beta,
    float* __restrict__ out, int b0) {
    __shared__ int sidx[32][8];
    __shared__ float swt[32][8];
    __shared__ float devt[32 * 129];
    int bid = blockIdx.x;
    int bl = bid >> 7;
    int b = b0 + bl;
    int n0 = (bid & 127) * 32;
    int tid = threadIdx.x;
    if (tid < 32) {
        int n = n0 + tid;
        const float* nc = ncoords + ((size_t)b * N_ + n) * 3;
        float fc[3] = {nc[0], nc[1], nc[2]};
        int i0[3], i1[3];
        float dd[3];
        for (int k = 0; k < 3; ++k) {
            float fl = floorf(fc[k]);
            i0[k] = (int)fl;
            i1[k] = min(i0[k] + 1, R_ - 1);
            dd[k] = fc[k] - fl;
        }
#pragma unroll
        for (int k = 0; k < 8; ++k) {
            int ix = (k >> 2) & 1, iy = (k >> 1) & 1, iz = k & 1;
            int xi = ix ? i1[0] : i0[0];
            int yi = iy ? i1[1] : i0[1];
            int zi = iz ? i1[2] : i0[2];
            sidx[tid][k] = (xi * R_ + yi) * R_ + zi;
            float wx = ix ? dd[0] : 1.0f - dd[0];
            float wy = iy ? dd[1] : 1.0f - dd[1];
            float wz = iz ? dd[2] : 1.0f - dd[2];
            swt[tid][k] = wx * wy * wz;
        }
    }
    __syncthreads();
    int co = tid & 127, pg = tid >> 7;
    int grp = co >> 4;
    const float cntv = 16.0f * N_;
    float mean = stats[(b * 8 + grp) * 2 + 0] / cntv;
    float var = stats[(b * 8 + grp) * 2 + 1] / cntv - mean * mean;
    float inv = rsqrtf(var + EPS_);
    float A = gamma[co] * inv, Bc = beta[co] - mean * A;
    const unsigned short* gp = grid + (size_t)bl * R3_ * 128 + co;
    for (int p = pg; p < 32; p += 2) {
        float acc = 0.f;
#pragma unroll
        for (int k = 0; k < 8; ++k) acc += swt[p][k] * b2f(gp[(size_t)sidx[p][k] * 128]);
        float x = b2f(pf[((size_t)bl * N_ + n0 + p) * 128 + co]);
        float s = A * x + Bc;
        devt[p * 129 + co] = acc + s / (1.0f + expf(-s));
    }
    __syncthreads();
    int pp = tid & 31, cg = tid >> 5;
    float* op = out + (size_t)b * 128 * N_ + n0 + pp;
    for (int c = cg * 16; c < cg * 16 + 16; ++c)
        op[(size_t)c * N_] = devt[pp * 129 + c];
}

extern "C" void kernel_launch(void* const* d_in, const int* in_sizes, int n_in,
                              void* d_out, int out_size, void* d_ws, size_t ws_size,
                              hipStream_t stream) {
    const float* features = (const float*)d_in[0];
    const float* coords = (const float*)d_in[1];
    const float* c1w = (const float*)d_in[2];
    const float* c1b = (const float*)d_in[3];
    const float* g1g = (const float*)d_in[4];
    const float* g1b = (const float*)d_in[5];
    const float* c2w = (const float*)d_in[6];
    const float* c2b = (const float*)d_in[7];
    const float* g2g = (const float*)d_in[8];
    const float* g2b = (const float*)d_in[9];
    const float* ptw = (const float*)d_in[10];
    const float* ptb = (const float*)d_in[11];
    const float* pgg = (const float*)d_in[12];
    const float* pgb = (const float*)d_in[13];
    float* outp = (float*)d_out;

    size_t globals = ((size_t)B_ * R3_ * 4 + 255 & ~(size_t)255)        // cnt
                   + ((size_t)B_ * N_ * 3 * 4 + 255 & ~(size_t)255)     // ncoords
                   + ((size_t)B_ * N_ * 4 + 255 & ~(size_t)255)         // flatidx
                   + 256 + 2048                                         // bstats, statsAll
                   + ((size_t)27 * 64 * 128 * 2 + 255 & ~(size_t)255)   // wp1
                   + ((size_t)27 * 128 * 128 * 2 + 255 & ~(size_t)255)  // wp2
                   + ((size_t)64 * 128 * 2 + 255 & ~(size_t)255)        // wpPt
                   + 8192;                                              // slack
    int CB = 1;
    for (int cb = 8; cb >= 1; cb >>= 1) {
        size_t need = globals
                    + ((size_t)cb * R3_ * 64 * 4)     // voxC (aliases gC bf16)
                    + ((size_t)cb * R3_ * 64 * 2)     // gA
                    + ((size_t)cb * R3_ * 128 * 2)    // gB
                    + ((size_t)cb * N_ * 128 * 2)     // pf bf16
                    + ((size_t)cb * 64 * N_ * 2);     // featbc
        if (need <= ws_size) { CB = cb; break; }
    }

    char* ws = (char*)d_ws;
    size_t o = 0;
    auto alloc = [&](size_t bytes) {
        size_t r = o;
        o += (bytes + 255) & ~(size_t)255;
        return r;
    };
    float* voxC = (float*)(ws + alloc((size_t)CB * R3_ * 64 * 4));  // also gC bf16
    unsigned short* gC = (unsigned short*)voxC;
    unsigned short* gA = (unsigned short*)(ws + alloc((size_t)CB * R3_ * 64 * 2));
    unsigned short* gB = (unsigned short*)(ws + alloc((size_t)CB * R3_ * 128 * 2));
    unsigned short* pfbuf = (unsigned short*)(ws + alloc((size_t)CB * N_ * 128 * 2));
    unsigned short* featbc = (unsigned short*)(ws + alloc((size_t)CB * 64 * N_ * 2));
    float* cnt = (float*)(ws + alloc((size_t)B_ * R3_ * 4));
    float* ncoords = (float*)(ws + alloc((size_t)B_ * N_ * 3 * 4));
    int* flatidx = (int*)(ws + alloc((size_t)B_ * N_ * 4));
    float* bstats = (float*)(ws + alloc(256));
    float* statsAll = (float*)(ws + alloc(2048));
    float* stats1 = statsAll;
    float* stats2 = statsAll + 128;
    float* statsPt = statsAll + 256;
    unsigned short* wp1 = (unsigned short*)(ws + alloc((size_t)27 * 64 * 128 * 2));
    unsigned short* wp2 = (unsigned short*)(ws + alloc((size_t)27 * 128 * 128 * 2));
    unsigned short* wpPt = (unsigned short*)(ws + alloc((size_t)64 * 128 * 2));

    // ---- globals (once per launch)
    hipMemsetAsync(cnt, 0, (size_t)B_ * R3_ * 4, stream);
    hipMemsetAsync(statsAll, 0, 1536, stream);
    k_wpack<<<(27 * 64 * 128 + 255) / 256, 256, 0, stream>>>(c1w, wp1, 64, 27);
    k_wpack<<<(27 * 128 * 128 + 255) / 256, 256, 0, stream>>>(c2w, wp2, 128, 27);
    k_wpack<<<(64 * 128 + 255) / 256, 256, 0, stream>>>(ptw, wpPt, 64, 1);
    k_batch_stats<<<B_, 256, 0, stream>>>(coords, bstats);
    k_points<<<B_ * N_ / 256, 256, 0, stream>>>(coords, bstats, ncoords, flatidx, cnt);

    // ---- per batch-chunk pipeline
    for (int b0 = 0; b0 < B_; b0 += CB) {
        hipMemsetAsync(voxC, 0, (size_t)CB * R3_ * 64 * 4, stream);
        k_feat2b<<<CB * 128, 256, 0, stream>>>(features, featbc, b0);
        k_scatter<<<CB * 64 * 16, 256, 0, stream>>>(features, flatidx, voxC, b0);
        k_divide<<<CB * 1024, 256, 0, stream>>>(voxC, cnt, gA, b0);
        k_conv_mfma<64><<<CB * 256, 256, 0, stream>>>(gA, wp1, c1b, gB, stats1, b0);
        k_gnswish<<<CB * 2048, 256, 0, stream>>>(gB, stats1, g1g, g1b, b0);
        k_conv_mfma<128><<<CB * 256, 256, 0, stream>>>(gB, wp2, c2b, gC, stats2, b0);
        k_gnswish<<<CB * 2048, 256, 0, stream>>>(gC, stats2, g2g, g2b, b0);
        k_point_mfma<<<CB * 16, 256, 0, stream>>>(featbc, wpPt, ptb, pfbuf, statsPt, b0);
        k_final<<<CB * 128, 256, 0, stream>>>(gC, ncoords, pfbuf, statsPt, pgg, pgb, outp, b0);
    }
}